// Round 4
// baseline (930.215 us; speedup 1.0000x reference)
//
#include <hip/hip_runtime.h>

typedef unsigned int u32;
typedef float f32x4 __attribute__((ext_vector_type(4)));
typedef _Float16 f16x8 __attribute__((ext_vector_type(8)));
typedef _Float16 f16x4 __attribute__((ext_vector_type(4)));
typedef _Float16 f16x2 __attribute__((ext_vector_type(2)));

static constexpr int kN = 500000;   // points
static constexpr int kC = 10000;    // clusters

// ---------- W -> f16 concat [384][128] (Wv|Wk|Wq) + bias concat ----------
__global__ void k_wcvt(const float* __restrict__ Wv, const float* __restrict__ Wk,
                       const float* __restrict__ Wq, const float* __restrict__ bv,
                       const float* __restrict__ bk, const float* __restrict__ bq,
                       _Float16* __restrict__ Wc, float* __restrict__ bias_c) {
  int i = blockIdx.x * blockDim.x + threadIdx.x;
  if (i < 384) bias_c[i] = (i < 128) ? bv[i] : (i < 256) ? bk[i - 128] : bq[i - 256];
  if (i >= 384 * 128) return;
  int row = i >> 7;
  float f = (row < 128) ? Wv[i] : (row < 256) ? Wk[i - 128 * 128] : Wq[i - 256 * 128];
  Wc[i] = (_Float16)f;
}

// ---------- counting sort by cluster (order only; no rank needed) ----------
__global__ void k_hist(const int* __restrict__ cluster, int* __restrict__ hist) {
  int n = blockIdx.x * blockDim.x + threadIdx.x;
  if (n < kN) atomicAdd(hist + cluster[n], 1);
}

__global__ void k_scan(const int* __restrict__ hist, int* __restrict__ offs,
                       int* __restrict__ cur) {
  __shared__ int sh[256];
  const int t = threadIdx.x;  // 256 threads
  const int b0 = t * 40;
  const int e0 = (b0 + 40 < kC) ? b0 + 40 : kC;
  int s = 0;
  for (int i = b0; i < e0; ++i) s += hist[i];
  sh[t] = s;
  __syncthreads();
  for (int d = 1; d < 256; d <<= 1) {
    int v = (t >= d) ? sh[t - d] : 0;
    __syncthreads();
    sh[t] += v;
    __syncthreads();
  }
  int run = sh[t] - s;  // exclusive prefix
  for (int i = b0; i < e0; ++i) {
    offs[i] = run;
    cur[i] = run;
    run += hist[i];
  }
}

__global__ void k_scatter(const int* __restrict__ cluster, int* __restrict__ cur,
                          int* __restrict__ order) {
  int n = blockIdx.x * blockDim.x + threadIdx.x;
  if (n < kN) {
    int pos = atomicAdd(cur + cluster[n], 1);
    order[pos] = n;
  }
}

// ---------- projections, NATURAL order: stream-read x, stream-write v/k/qp ----------
// Wave owns 16 consecutive points. A=W[384x128], B=x^T. acc[24] covers all 384
// output dims in registers; LDS transpose -> 3x 4KB contiguous dwordx4 stores.
__global__ __launch_bounds__(256, 3) void k_proj(
    const float* __restrict__ x, const _Float16* __restrict__ Wc,
    const float* __restrict__ bias_c, _Float16* __restrict__ v_nat,
    _Float16* __restrict__ k_nat, _Float16* __restrict__ qp_nat) {
  __shared__ _Float16 lds[4][16][400];  // 400 = 384 + 16 pad (16B-aligned rows)
  const int lane = threadIdx.x & 63, wid = threadIdx.x >> 6;
  const int g = lane >> 4, r = lane & 15;
  const long pbase = (long)blockIdx.x * 64 + wid * 16;

  // B frags: x[pbase+r][kk*32+8g+j], consecutive rows -> coalesced reads
  f16x8 xf[4];
  {
    long row = pbase + r;
    if (row >= kN) row = kN - 1;
    const float* xp = x + row * 128;
#pragma unroll
    for (int kk = 0; kk < 4; ++kk) {
      float4 f0 = *(const float4*)(xp + kk * 32 + g * 8);
      float4 f1 = *(const float4*)(xp + kk * 32 + g * 8 + 4);
      f16x8 h;
      h[0] = (_Float16)f0.x; h[1] = (_Float16)f0.y;
      h[2] = (_Float16)f0.z; h[3] = (_Float16)f0.w;
      h[4] = (_Float16)f1.x; h[5] = (_Float16)f1.y;
      h[6] = (_Float16)f1.z; h[7] = (_Float16)f1.w;
      xf[kk] = h;
    }
  }

  f32x4 acc[24];
#pragma unroll
  for (int m = 0; m < 24; ++m) acc[m] = (f32x4){0.f, 0.f, 0.f, 0.f};
#pragma unroll
  for (int m = 0; m < 24; ++m) {
    const _Float16* wrow = Wc + (m * 16 + r) * 128;
#pragma unroll
    for (int kk = 0; kk < 4; ++kk) {
      f16x8 wf = *(const f16x8*)(wrow + kk * 32 + g * 8);
      acc[m] = __builtin_amdgcn_mfma_f32_16x16x32_f16(wf, xf[kk], acc[m], 0, 0, 0);
    }
  }

  // epilogue: bias + f16 pack into LDS (lane holds dims m*16+4g..+3 of point r)
#pragma unroll
  for (int m = 0; m < 24; ++m) {
    float4 b4 = *(const float4*)(bias_c + m * 16 + g * 4);
    f16x4 h;
    h[0] = (_Float16)(acc[m][0] + b4.x);
    h[1] = (_Float16)(acc[m][1] + b4.y);
    h[2] = (_Float16)(acc[m][2] + b4.z);
    h[3] = (_Float16)(acc[m][3] + b4.w);
    *(f16x4*)&lds[wid][r][m * 16 + g * 4] = h;
  }
  __syncthreads();

  // store: per matrix, wave writes a contiguous 4KB chunk (16 rows x 256B)
#pragma unroll
  for (int mat = 0; mat < 3; ++mat) {
    _Float16* outp = (mat == 0) ? v_nat : (mat == 1) ? k_nat : qp_nat;
#pragma unroll
    for (int s = 0; s < 4; ++s) {
      int flat = s * 1024 + lane * 16;  // byte offset within the 4KB chunk
      int row = flat >> 8;              // 0..15
      int colh = (flat & 255) >> 1;     // half-offset within 256B row
      long gp = pbase + row;
      if (gp < kN) {
        f16x8 val = *(const f16x8*)&lds[wid][row][mat * 128 + colh];
        *(f16x8*)(outp + gp * 128 + colh) = val;
      }
    }
  }
}

// ---------- fused per-cluster: q = max-pool(qp), M = q.k, softmax -> a_nat ----------
__global__ __launch_bounds__(256) void k_attn(
    const _Float16* __restrict__ qp, const _Float16* __restrict__ k_,
    const int* __restrict__ order, const int* __restrict__ offs,
    const int* __restrict__ hist, float* __restrict__ M_s,
    float* __restrict__ a_nat) {
  __shared__ float q_sh[128];
  __shared__ float red[512];
  const int c = blockIdx.x;
  const int start = offs[c], cnt = hist[c];
  if (cnt == 0) return;
  const int t = threadIdx.x, lane = t & 63, wid = t >> 6;
  // phase 1: per-dim max over the cluster's qp rows (gather via order)
  {
    const int d2 = lane * 2;
    float m0 = -INFINITY, m1 = -INFINITY;
    for (int i = wid; i < cnt; i += 4) {
      int n = order[start + i];
      f16x2 h = *(const f16x2*)(qp + (long)n * 128 + d2);
      m0 = fmaxf(m0, (float)h[0]);
      m1 = fmaxf(m1, (float)h[1]);
    }
    red[t] = m0;
    red[t + 256] = m1;
  }
  __syncthreads();
  if (t < 64) {
    float q0 = fmaxf(fmaxf(red[t], red[t + 64]), fmaxf(red[t + 128], red[t + 192]));
    float q1 = fmaxf(fmaxf(red[t + 256], red[t + 320]), fmaxf(red[t + 384], red[t + 448]));
    q_sh[2 * t] = q0;
    q_sh[2 * t + 1] = q1;
  }
  __syncthreads();
  // phase 2: M_i = dot(q, k_i); track max
  float wmax = -INFINITY;
  {
    const float q0 = q_sh[lane * 2], q1 = q_sh[lane * 2 + 1];
    for (int i = wid; i < cnt; i += 4) {
      int n = order[start + i];
      f16x2 h = *(const f16x2*)(k_ + (long)n * 128 + lane * 2);
      float p = fmaf(q0, (float)h[0], q1 * (float)h[1]);
#pragma unroll
      for (int off = 32; off; off >>= 1) p += __shfl_xor(p, off, 64);
      if (lane == 0) M_s[start + i] = p;
      wmax = fmaxf(wmax, p);
    }
  }
  if (lane == 0) red[wid] = wmax;
  __syncthreads();
  const float m = fmaxf(fmaxf(red[0], red[1]), fmaxf(red[2], red[3]));
  // phase 3: e = exp(M-m); s = sum; a_nat[order[i]] = e/s
  float lsum = 0.f;
  for (int i = t; i < cnt; i += 256) {
    float e = __expf(M_s[start + i] - m);
    M_s[start + i] = e;
    lsum += e;
  }
#pragma unroll
  for (int off = 32; off; off >>= 1) lsum += __shfl_xor(lsum, off, 64);
  if (lane == 0) red[4 + wid] = lsum;
  __syncthreads();
  const float inv = 1.f / (red[4] + red[5] + red[6] + red[7]);
  for (int i = t; i < cnt; i += 256)
    a_nat[order[start + i]] = M_s[start + i] * inv;
}

// ---------- BN stats: per-block partial sums of y, y^2 per dim (streaming) ----------
__global__ __launch_bounds__(256) void k_bnstats(
    const _Float16* __restrict__ v_nat, const float* __restrict__ a_nat,
    float* __restrict__ part_mu, float* __restrict__ part_m2) {
  const int t = threadIdx.x;
  const int d2 = (t & 63) * 2, rg = t >> 6;
  float s0 = 0.f, s1 = 0.f, p0 = 0.f, p1 = 0.f;
  for (long base = (long)blockIdx.x * 4; base < kN; base += (long)gridDim.x * 4) {
    long row = base + rg;
    if (row < kN) {
      float a = a_nat[row];
      f16x2 h = *(const f16x2*)(v_nat + row * 128 + d2);
      float y0 = a * (float)h[0], y1 = a * (float)h[1];
      s0 += y0; s1 += y1; p0 += y0 * y0; p1 += y1 * y1;
    }
  }
  __shared__ float red[1024];
  red[t] = s0; red[t + 256] = s1; red[t + 512] = p0; red[t + 768] = p1;
  __syncthreads();
  if (t < 64) {
    float a0 = red[t] + red[t + 64] + red[t + 128] + red[t + 192];
    float a1 = red[t + 256] + red[t + 320] + red[t + 384] + red[t + 448];
    float b0 = red[t + 512] + red[t + 576] + red[t + 640] + red[t + 704];
    float b1 = red[t + 768] + red[t + 832] + red[t + 896] + red[t + 960];
    part_mu[blockIdx.x * 128 + 2 * t] = a0;
    part_mu[blockIdx.x * 128 + 2 * t + 1] = a1;
    part_m2[blockIdx.x * 128 + 2 * t] = b0;
    part_m2[blockIdx.x * 128 + 2 * t + 1] = b1;
  }
}

// ---------- reduce partials (f64), produce scale/shift ----------
__global__ void k_bnred(const float* __restrict__ part_mu, const float* __restrict__ part_m2,
                        const float* __restrict__ gamma, const float* __restrict__ beta,
                        float* __restrict__ scale, float* __restrict__ shift) {
  const int d = threadIdx.x;  // 128
  double mu = 0.0, m2 = 0.0;
  for (int b = 0; b < 1024; ++b) {
    mu += (double)part_mu[b * 128 + d];
    m2 += (double)part_m2[b * 128 + d];
  }
  mu /= (double)kN;
  double var = m2 / (double)kN - mu * mu;
  double inv = 1.0 / sqrt(var + 1e-5);
  float sc = gamma[d] * (float)inv;
  scale[d] = sc;
  shift[d] = beta[d] - (float)mu * sc;
}

// ---------- out = leakyrelu((a*v)*scale + shift), all natural/streaming ----------
__global__ __launch_bounds__(256) void k_out(
    const _Float16* __restrict__ v_nat, const float* __restrict__ a_nat,
    const float* __restrict__ scale, const float* __restrict__ shift,
    float* __restrict__ out) {
  long i = (long)blockIdx.x * blockDim.x + threadIdx.x;  // kN*32 chunks of 4 dims
  if (i >= (long)kN * 32) return;
  long n = i >> 5;
  int c4 = (int)(i & 31) * 4;
  float a = a_nat[n];
  f16x4 h = *(const f16x4*)(v_nat + n * 128 + c4);
  float4 sc = *(const float4*)(scale + c4);
  float4 sh = *(const float4*)(shift + c4);
  float4 o;
  o.x = fmaf(a * (float)h[0], sc.x, sh.x);
  o.y = fmaf(a * (float)h[1], sc.y, sh.y);
  o.z = fmaf(a * (float)h[2], sc.z, sh.z);
  o.w = fmaf(a * (float)h[3], sc.w, sh.w);
  o.x = o.x >= 0.f ? o.x : 0.2f * o.x;
  o.y = o.y >= 0.f ? o.y : 0.2f * o.y;
  o.z = o.z >= 0.f ? o.z : 0.2f * o.z;
  o.w = o.w >= 0.f ? o.w : 0.2f * o.w;
  *(float4*)(out + n * 128 + c4) = o;
}

extern "C" void kernel_launch(void* const* d_in, const int* in_sizes, int n_in,
                              void* d_out, int out_size, void* d_ws, size_t ws_size,
                              hipStream_t stream) {
  const float* x = (const float*)d_in[0];
  const int* cluster = (const int*)d_in[1];
  const float* Wv = (const float*)d_in[2];
  const float* bv = (const float*)d_in[3];
  const float* Wk = (const float*)d_in[4];
  const float* bk = (const float*)d_in[5];
  const float* Wq = (const float*)d_in[6];
  const float* bq = (const float*)d_in[7];
  const float* gamma = (const float*)d_in[8];
  const float* beta = (const float*)d_in[9];
  float* out = (float*)d_out;

  char* ws = (char*)d_ws;
  // layout (bytes)
  _Float16* Wc = (_Float16*)(ws + 0);        //    98,304
  float* bias_c = (float*)(ws + 98304);      //     1,536 -> 99,840
  int* hist = (int*)(ws + 99840);            //    40,000 -> 139,840
  int* offs = (int*)(ws + 139840);           //    40,000 -> 179,840
  int* cur = (int*)(ws + 179840);            //    40,000 -> 219,840
  float* scale = (float*)(ws + 219840);      //       512 -> 220,352
  float* shift = (float*)(ws + 220352);      //       512 -> 220,864
  float* M_s = (float*)(ws + 220864);        // 2,000,000 -> 2,220,864
  float* a_nat = (float*)(ws + 2220864);     // 2,000,000 -> 4,220,864
  int* order = (int*)(ws + 4220864);         // 2,000,000 -> 6,220,864
  float* part_mu = (float*)(ws + 6220864);   //   524,288 -> 6,745,152
  float* part_m2 = (float*)(ws + 6745152);   //   524,288 -> 7,269,440
  _Float16* v_nat = (_Float16*)(ws + 7269440);    // 128,000,000 -> 135,269,440
  _Float16* k_nat = (_Float16*)(ws + 135269440);  // 128,000,000 -> 263,269,440
  // qp (f16, natural order) lives in d_out until k_out overwrites it
  _Float16* qp_nat = (_Float16*)d_out;

  hipMemsetAsync(hist, 0, 40000, stream);  // only hist needs zeroing

  k_wcvt<<<192, 256, 0, stream>>>(Wv, Wk, Wq, bv, bk, bq, Wc, bias_c);
  k_hist<<<(kN + 255) / 256, 256, 0, stream>>>(cluster, hist);
  k_scan<<<1, 256, 0, stream>>>(hist, offs, cur);
  k_scatter<<<(kN + 255) / 256, 256, 0, stream>>>(cluster, cur, order);
  k_proj<<<(kN + 63) / 64, 256, 0, stream>>>(x, Wc, bias_c, v_nat, k_nat, qp_nat);
  k_attn<<<kC, 256, 0, stream>>>(qp_nat, k_nat, order, offs, hist, M_s, a_nat);
  k_bnstats<<<1024, 256, 0, stream>>>(v_nat, a_nat, part_mu, part_m2);
  k_bnred<<<1, 128, 0, stream>>>(part_mu, part_m2, gamma, beta, scale, shift);
  k_out<<<(int)(((long)kN * 32 + 255) / 256), 256, 0, stream>>>(v_nat, a_nat, scale,
                                                                shift, out);
}

// Round 5
// 569.872 us; speedup vs baseline: 1.6323x; 1.6323x over previous
//
#include <hip/hip_runtime.h>

typedef unsigned int u32;
typedef float f32x4 __attribute__((ext_vector_type(4)));
typedef _Float16 f16x8 __attribute__((ext_vector_type(8)));
typedef _Float16 f16x4 __attribute__((ext_vector_type(4)));
typedef _Float16 f16x2 __attribute__((ext_vector_type(2)));

static constexpr int kN = 500000;   // points
static constexpr int kC = 10000;    // clusters

// ---------- W -> f16 concat [384][128] (Wv|Wk|Wq) + bias concat ----------
__global__ void k_wcvt(const float* __restrict__ Wv, const float* __restrict__ Wk,
                       const float* __restrict__ Wq, const float* __restrict__ bv,
                       const float* __restrict__ bk, const float* __restrict__ bq,
                       _Float16* __restrict__ Wc, float* __restrict__ bias_c) {
  int i = blockIdx.x * blockDim.x + threadIdx.x;
  if (i < 384) bias_c[i] = (i < 128) ? bv[i] : (i < 256) ? bk[i - 128] : bq[i - 256];
  if (i >= 384 * 128) return;
  int row = i >> 7;
  float f = (row < 128) ? Wv[i] : (row < 256) ? Wk[i - 128 * 128] : Wq[i - 256 * 128];
  Wc[i] = (_Float16)f;
}

// ---------- counting sort by cluster: order (sorted->natural) + rank (natural->sorted) ----------
__global__ void k_hist(const int* __restrict__ cluster, int* __restrict__ hist) {
  int n = blockIdx.x * blockDim.x + threadIdx.x;
  if (n < kN) atomicAdd(hist + cluster[n], 1);
}

__global__ void k_scan(const int* __restrict__ hist, int* __restrict__ offs,
                       int* __restrict__ cur) {
  __shared__ int sh[256];
  const int t = threadIdx.x;  // 256 threads
  const int b0 = t * 40;
  const int e0 = (b0 + 40 < kC) ? b0 + 40 : kC;
  int s = 0;
  for (int i = b0; i < e0; ++i) s += hist[i];
  sh[t] = s;
  __syncthreads();
  for (int d = 1; d < 256; d <<= 1) {
    int v = (t >= d) ? sh[t - d] : 0;
    __syncthreads();
    sh[t] += v;
    __syncthreads();
  }
  int run = sh[t] - s;  // exclusive prefix
  for (int i = b0; i < e0; ++i) {
    offs[i] = run;
    cur[i] = run;
    run += hist[i];
  }
}

__global__ void k_scatter(const int* __restrict__ cluster, int* __restrict__ cur,
                          int* __restrict__ order, int* __restrict__ rank) {
  int n = blockIdx.x * blockDim.x + threadIdx.x;
  if (n < kN) {
    int pos = atomicAdd(cur + cluster[n], 1);
    order[pos] = n;
    rank[n] = pos;
  }
}

// ---------- projections ----------
// Wave owns 64 consecutive (natural) points; streams x; all 24 m-tiles looped in
// 6 groups of 64 dims. Wave-PRIVATE LDS staging (no barriers); flush per group:
// v -> natural rows (contiguous), k/qp -> sorted rows (scattered 128B chunks).
__global__ __launch_bounds__(256, 2) void k_proj(
    const float* __restrict__ x, const int* __restrict__ rank,
    const _Float16* __restrict__ Wc, const float* __restrict__ bias_c,
    _Float16* __restrict__ v_nat, _Float16* __restrict__ k_srt,
    _Float16* __restrict__ qp_srt) {
  __shared__ _Float16 stg[4][64][72];  // per-wave 9216B; 36,864B total
  const int lane = threadIdx.x & 63, wid = threadIdx.x >> 6;
  const int g = lane >> 4, r = lane & 15;
  const long pbase = (long)blockIdx.x * 256 + wid * 64;

  long myp = pbase + lane;
  if (myp >= kN) myp = kN - 1;
  const int myrank = rank[myp];

  // B-frags: x[pbase+p*16+r][kk*32+8g+j] (streaming, coalesced)
  f16x8 xf[4][4];
#pragma unroll
  for (int p = 0; p < 4; ++p) {
    long row = pbase + p * 16 + r;
    if (row >= kN) row = kN - 1;
    const float* xp = x + row * 128;
#pragma unroll
    for (int kk = 0; kk < 4; ++kk) {
      float4 f0 = *(const float4*)(xp + kk * 32 + g * 8);
      float4 f1 = *(const float4*)(xp + kk * 32 + g * 8 + 4);
      f16x8 h;
      h[0] = (_Float16)f0.x; h[1] = (_Float16)f0.y;
      h[2] = (_Float16)f0.z; h[3] = (_Float16)f0.w;
      h[4] = (_Float16)f1.x; h[5] = (_Float16)f1.y;
      h[6] = (_Float16)f1.z; h[7] = (_Float16)f1.w;
      xf[p][kk] = h;
    }
  }

#pragma unroll
  for (int mg = 0; mg < 6; ++mg) {  // 64-dim groups
#pragma unroll
    for (int mu = 0; mu < 4; ++mu) {
      const int mt = mg * 4 + mu;
      const _Float16* wrow = Wc + (mt * 16 + r) * 128;
      f16x8 wf[4];
#pragma unroll
      for (int kk = 0; kk < 4; ++kk)
        wf[kk] = *(const f16x8*)(wrow + kk * 32 + g * 8);
      float4 b4 = *(const float4*)(bias_c + mt * 16 + g * 4);
#pragma unroll
      for (int p = 0; p < 4; ++p) {
        f32x4 acc = {0.f, 0.f, 0.f, 0.f};
#pragma unroll
        for (int kk = 0; kk < 4; ++kk)
          acc = __builtin_amdgcn_mfma_f32_16x16x32_f16(wf[kk], xf[p][kk], acc, 0, 0, 0);
        f16x4 h;
        h[0] = (_Float16)(acc[0] + b4.x);
        h[1] = (_Float16)(acc[1] + b4.y);
        h[2] = (_Float16)(acc[2] + b4.z);
        h[3] = (_Float16)(acc[3] + b4.w);
        *(f16x4*)&stg[wid][p * 16 + r][mu * 16 + g * 4] = h;
      }
    }
    // flush group: 64 pts x 128B; v natural (contig), k/qp sorted (scatter)
    _Float16* arr = (mg < 2) ? v_nat : (mg < 4) ? k_srt : qp_srt;
    const bool srt = (mg >= 2);
    const int off = (mg & 1) * 64;
#pragma unroll
    for (int s = 0; s < 8; ++s) {
      const int pl = 8 * s + (lane >> 3);
      const long pt = pbase + pl;
      if (pt < kN) {
        f16x8 val = *(const f16x8*)&stg[wid][pl][(lane & 7) * 8];
        const long row = srt ? (long)__shfl(myrank, pl, 64) : pt;
        *(f16x8*)(arr + row * 128 + off + (lane & 7) * 8) = val;
      }
    }
  }
}

// ---------- fused per-cluster attention: ALL STREAMING (sorted qp/k) ----------
__global__ __launch_bounds__(256) void k_attn(
    const _Float16* __restrict__ qp_s, const _Float16* __restrict__ k_s,
    const int* __restrict__ offs, const int* __restrict__ hist,
    const int* __restrict__ order, float* __restrict__ M_glob,
    float* __restrict__ a_nat) {
  __shared__ float q_sh[128];
  __shared__ float red[512];
  __shared__ float Mld[1024];
  const int c = blockIdx.x;
  const int start = offs[c], cnt = hist[c];
  if (cnt == 0) return;
  const int t = threadIdx.x, lane = t & 63, wid = t >> 6;
  const bool fits = (cnt <= 1024);
  // phase 1: per-dim max over cluster's qp rows (streaming)
  {
    const int d2 = lane * 2;
    float m0 = -1e30f, m1 = -1e30f;
    for (int i = wid; i < cnt; i += 4) {
      f16x2 h = *(const f16x2*)(qp_s + (long)(start + i) * 128 + d2);
      m0 = fmaxf(m0, (float)h[0]);
      m1 = fmaxf(m1, (float)h[1]);
    }
    red[t] = m0;
    red[t + 256] = m1;
  }
  __syncthreads();
  if (t < 64) {
    float q0 = fmaxf(fmaxf(red[t], red[t + 64]), fmaxf(red[t + 128], red[t + 192]));
    float q1 = fmaxf(fmaxf(red[t + 256], red[t + 320]), fmaxf(red[t + 384], red[t + 448]));
    q_sh[2 * t] = q0;
    q_sh[2 * t + 1] = q1;
  }
  __syncthreads();
  // phase 2: M_i = dot(q, k_i) (streaming); track max
  float wmax = -1e30f;
  {
    const float q0 = q_sh[lane * 2], q1 = q_sh[lane * 2 + 1];
    for (int i = wid; i < cnt; i += 4) {
      f16x2 h = *(const f16x2*)(k_s + (long)(start + i) * 128 + lane * 2);
      float p = fmaf(q0, (float)h[0], q1 * (float)h[1]);
#pragma unroll
      for (int off = 32; off; off >>= 1) p += __shfl_xor(p, off, 64);
      if (lane == 0) {
        if (fits) Mld[i] = p; else M_glob[start + i] = p;
      }
      wmax = fmaxf(wmax, p);
    }
  }
  if (lane == 0) red[wid] = wmax;
  __syncthreads();
  const float m = fmaxf(fmaxf(red[0], red[1]), fmaxf(red[2], red[3]));
  // phase 3: e = exp(M-m); s = sum; a_nat[order[i]] = e/s (4B scatter)
  float lsum = 0.f;
  for (int i = t; i < cnt; i += 256) {
    float Mi = fits ? Mld[i] : M_glob[start + i];
    float e = __expf(Mi - m);
    if (fits) Mld[i] = e; else M_glob[start + i] = e;
    lsum += e;
  }
#pragma unroll
  for (int off = 32; off; off >>= 1) lsum += __shfl_xor(lsum, off, 64);
  if (lane == 0) red[4 + wid] = lsum;
  __syncthreads();
  const float inv = 1.f / (red[4] + red[5] + red[6] + red[7]);
  for (int i = t; i < cnt; i += 256) {
    float e = fits ? Mld[i] : M_glob[start + i];
    a_nat[order[start + i]] = e * inv;
  }
}

// ---------- BN stats: per-block partial sums of y, y^2 per dim (streaming) ----------
__global__ __launch_bounds__(256) void k_bnstats(
    const _Float16* __restrict__ v_nat, const float* __restrict__ a_nat,
    float* __restrict__ part_mu, float* __restrict__ part_m2) {
  const int t = threadIdx.x;
  const int d2 = (t & 63) * 2, rg = t >> 6;
  float s0 = 0.f, s1 = 0.f, p0 = 0.f, p1 = 0.f;
  for (long base = (long)blockIdx.x * 4; base < kN; base += (long)gridDim.x * 4) {
    long row = base + rg;
    if (row < kN) {
      float a = a_nat[row];
      f16x2 h = *(const f16x2*)(v_nat + row * 128 + d2);
      float y0 = a * (float)h[0], y1 = a * (float)h[1];
      s0 += y0; s1 += y1; p0 += y0 * y0; p1 += y1 * y1;
    }
  }
  __shared__ float red[1024];
  red[t] = s0; red[t + 256] = s1; red[t + 512] = p0; red[t + 768] = p1;
  __syncthreads();
  if (t < 64) {
    float a0 = red[t] + red[t + 64] + red[t + 128] + red[t + 192];
    float a1 = red[t + 256] + red[t + 320] + red[t + 384] + red[t + 448];
    float b0 = red[t + 512] + red[t + 576] + red[t + 640] + red[t + 704];
    float b1 = red[t + 768] + red[t + 832] + red[t + 896] + red[t + 960];
    part_mu[blockIdx.x * 128 + 2 * t] = a0;
    part_mu[blockIdx.x * 128 + 2 * t + 1] = a1;
    part_m2[blockIdx.x * 128 + 2 * t] = b0;
    part_m2[blockIdx.x * 128 + 2 * t + 1] = b1;
  }
}

// ---------- reduce partials (parallel: one block per dim) ----------
__global__ void k_bnred(const float* __restrict__ part_mu, const float* __restrict__ part_m2,
                        const float* __restrict__ gamma, const float* __restrict__ beta,
                        float* __restrict__ scale, float* __restrict__ shift) {
  __shared__ float smu[256], sm2[256];
  const int d = blockIdx.x;   // 128 blocks
  const int t = threadIdx.x;  // 256 threads
  float mu = 0.f, m2 = 0.f;
  for (int b = t; b < 1024; b += 256) {
    mu += part_mu[b * 128 + d];
    m2 += part_m2[b * 128 + d];
  }
  smu[t] = mu;
  sm2[t] = m2;
  __syncthreads();
  for (int s2 = 128; s2; s2 >>= 1) {
    if (t < s2) { smu[t] += smu[t + s2]; sm2[t] += sm2[t + s2]; }
    __syncthreads();
  }
  if (t == 0) {
    float muv = smu[0] / (float)kN;
    float var = sm2[0] / (float)kN - muv * muv;
    float inv = rsqrtf(var + 1e-5f);
    float sc = gamma[d] * inv;
    scale[d] = sc;
    shift[d] = beta[d] - muv * sc;
  }
}

// ---------- out = leakyrelu((a*v)*scale + shift), all natural/streaming ----------
__global__ __launch_bounds__(256) void k_out(
    const _Float16* __restrict__ v_nat, const float* __restrict__ a_nat,
    const float* __restrict__ scale, const float* __restrict__ shift,
    float* __restrict__ out) {
  long i = (long)blockIdx.x * blockDim.x + threadIdx.x;  // kN*32 chunks of 4 dims
  if (i >= (long)kN * 32) return;
  long n = i >> 5;
  int c4 = (int)(i & 31) * 4;
  float a = a_nat[n];
  f16x4 h = *(const f16x4*)(v_nat + n * 128 + c4);
  float4 sc = *(const float4*)(scale + c4);
  float4 sh = *(const float4*)(shift + c4);
  float4 o;
  o.x = fmaf(a * (float)h[0], sc.x, sh.x);
  o.y = fmaf(a * (float)h[1], sc.y, sh.y);
  o.z = fmaf(a * (float)h[2], sc.z, sh.z);
  o.w = fmaf(a * (float)h[3], sc.w, sh.w);
  o.x = o.x >= 0.f ? o.x : 0.2f * o.x;
  o.y = o.y >= 0.f ? o.y : 0.2f * o.y;
  o.z = o.z >= 0.f ? o.z : 0.2f * o.z;
  o.w = o.w >= 0.f ? o.w : 0.2f * o.w;
  *(float4*)(out + n * 128 + c4) = o;
}

extern "C" void kernel_launch(void* const* d_in, const int* in_sizes, int n_in,
                              void* d_out, int out_size, void* d_ws, size_t ws_size,
                              hipStream_t stream) {
  const float* x = (const float*)d_in[0];
  const int* cluster = (const int*)d_in[1];
  const float* Wv = (const float*)d_in[2];
  const float* bv = (const float*)d_in[3];
  const float* Wk = (const float*)d_in[4];
  const float* bk = (const float*)d_in[5];
  const float* Wq = (const float*)d_in[6];
  const float* bq = (const float*)d_in[7];
  const float* gamma = (const float*)d_in[8];
  const float* beta = (const float*)d_in[9];
  float* out = (float*)d_out;

  char* ws = (char*)d_ws;
  // layout (bytes)
  _Float16* Wc = (_Float16*)(ws + 0);        //    98,304
  float* bias_c = (float*)(ws + 98304);      //     1,536 -> 99,840
  int* hist = (int*)(ws + 99840);            //    40,000 -> 139,840
  int* offs = (int*)(ws + 139840);           //    40,000 -> 179,840
  int* cur = (int*)(ws + 179840);            //    40,000 -> 219,840
  float* scale = (float*)(ws + 219840);      //       512 -> 220,352
  float* shift = (float*)(ws + 220352);      //       512 -> 220,864
  float* M_glob = (float*)(ws + 220864);     // 2,000,000 -> 2,220,864
  float* a_nat = (float*)(ws + 2220864);     // 2,000,000 -> 4,220,864
  int* order = (int*)(ws + 4220864);         // 2,000,000 -> 6,220,864
  int* rank = (int*)(ws + 6220864);          // 2,000,000 -> 8,220,864
  float* part_mu = (float*)(ws + 8220864);   //   524,288 -> 8,745,152
  float* part_m2 = (float*)(ws + 8745152);   //   524,288 -> 9,269,440
  _Float16* v_nat = (_Float16*)(ws + 9269440);    // 128,000,000 -> 137,269,440
  _Float16* k_srt = (_Float16*)(ws + 137269440);  // 128,000,000 -> 265,269,440
  // qp (f16, SORTED order) lives in d_out until k_out overwrites it
  _Float16* qp_srt = (_Float16*)d_out;

  hipMemsetAsync(hist, 0, 40000, stream);  // only hist needs zeroing

  k_wcvt<<<192, 256, 0, stream>>>(Wv, Wk, Wq, bv, bk, bq, Wc, bias_c);
  k_hist<<<(kN + 255) / 256, 256, 0, stream>>>(cluster, hist);
  k_scan<<<1, 256, 0, stream>>>(hist, offs, cur);
  k_scatter<<<(kN + 255) / 256, 256, 0, stream>>>(cluster, cur, order, rank);
  k_proj<<<(kN + 255) / 256, 256, 0, stream>>>(x, rank, Wc, bias_c, v_nat, k_srt, qp_srt);
  k_attn<<<kC, 256, 0, stream>>>(qp_srt, k_srt, offs, hist, order, M_glob, a_nat);
  k_bnstats<<<1024, 256, 0, stream>>>(v_nat, a_nat, part_mu, part_m2);
  k_bnred<<<128, 256, 0, stream>>>(part_mu, part_m2, gamma, beta, scale, shift);
  k_out<<<(int)(((long)kN * 32 + 255) / 256), 256, 0, stream>>>(v_nat, a_nat, scale,
                                                                shift, out);
}